// Round 1
// baseline (2853.656 us; speedup 1.0000x reference)
//
#include <hip/hip_runtime.h>
#include <stdint.h>

// ---------------- types ----------------
typedef __attribute__((ext_vector_type(8))) short bf16x8;   // 8 x bf16 = 4 VGPRs
typedef __attribute__((ext_vector_type(4))) short s16x4;    // 4 x bf16 = 8B
typedef __attribute__((ext_vector_type(4))) float f32x4;

#define AS1 __attribute__((address_space(1)))
#define AS3 __attribute__((address_space(3)))

static __device__ __forceinline__ void gload_lds16(const void* g, void* l) {
  __builtin_amdgcn_global_load_lds((const AS1 unsigned int*)g,
                                   (AS3 unsigned int*)l, 16, 0, 0);
}

// round-to-nearest-even f32 -> bf16 bits
static __device__ __forceinline__ short f2bs(float f) {
  unsigned u = __builtin_bit_cast(unsigned, f);
  unsigned r = (u + 0x7fffu + ((u >> 16) & 1u)) >> 16;
  return (short)r;
}

static __device__ __forceinline__ float sigmoid_f(float x) {
  return 1.0f / (1.0f + __expf(-x));
}
static __device__ __forceinline__ float tanh_f(float x) {
  float ax = fabsf(x);
  float e  = __expf(-2.0f * ax);
  float t  = (1.0f - e) / (1.0f + e);
  return copysignf(t, x);
}

// constants
#define BATCH 256
#define HID   512
#define STEPS 256
#define G3    1536   // 3*HID

// ---------------- fp32 -> bf16 convert (weights) ----------------
__global__ __launch_bounds__(256) void convert_kernel(const float* __restrict__ src,
                                                      short* __restrict__ dst, int n4) {
  int i = blockIdx.x * 256 + threadIdx.x;
  if (i < n4) {
    float4 v = *(const float4*)(src + (size_t)i * 4);
    s16x4 o;
    o[0] = f2bs(v.x); o[1] = f2bs(v.y); o[2] = f2bs(v.z); o[3] = f2bs(v.w);
    *(s16x4*)(dst + (size_t)i * 4) = o;
  }
}

// ---------------- x[b][i][s] f32  ->  xT[s][b][i] bf16 ----------------
__global__ __launch_bounds__(256) void transpose_kernel(const float* __restrict__ x,
                                                        short* __restrict__ xT) {
  int bx = blockIdx.x;
  int st = bx & 7, it = (bx >> 3) & 15, b = bx >> 7;
  int s0 = st * 32, i0 = it * 32;
  int tid = threadIdx.x;
  __shared__ float tile[32][33];
  int il = tid >> 3, s4 = (tid & 7) * 4;
  float4 v = *(const float4*)(x + (size_t)b * 131072 + (size_t)(i0 + il) * 256 + s0 + s4);
  tile[il][s4 + 0] = v.x; tile[il][s4 + 1] = v.y;
  tile[il][s4 + 2] = v.z; tile[il][s4 + 3] = v.w;
  __syncthreads();
  int sl = tid >> 3, iv = (tid & 7) * 4;
  s16x4 o;
  o[0] = f2bs(tile[iv + 0][sl]); o[1] = f2bs(tile[iv + 1][sl]);
  o[2] = f2bs(tile[iv + 2][sl]); o[3] = f2bs(tile[iv + 3][sl]);
  *(s16x4*)(xT + (size_t)(s0 + sl) * 131072 + (size_t)b * 512 + i0 + iv) = o;
}

// ---------------- phase 1: gi[m][g] = xT[m] . W_ih[g] + bias_ih[g] ----------------
// C[M x 1536] = A[M x 512] * B[1536 x 512]^T ; 128x128 tiles, BK=32, 256 thr (4 waves)
__global__ __launch_bounds__(256) void phase1_kernel(const short* __restrict__ A,
                                                     const short* __restrict__ B,
                                                     const float* __restrict__ bias,
                                                     float* __restrict__ out, int M) {
  int MT = M >> 7;
  int bx = blockIdx.x;
  int mt = bx % MT, nt = bx / MT;
  int m0 = mt * 128, n0 = nt * 128;
  int tid = threadIdx.x, w = tid >> 6, lane = tid & 63;
  int lm = lane & 15, q = lane >> 4;
  int wm = w & 1, wn = w >> 1;
  __shared__ short As[128 * 32];
  __shared__ short Bs[128 * 32];
  f32x4 acc[4][4] = {};
  int srow = lane >> 2;          // 0..15
  int scol = (lane & 3) * 8;     // element offset within 32

  for (int kt = 0; kt < 16; ++kt) {
#pragma unroll
    for (int i2 = 0; i2 < 2; ++i2) {
      int i = w * 2 + i2;
      int row = i * 16 + srow;
      gload_lds16(A + (size_t)(m0 + row) * 512 + kt * 32 + scol, As + i * 512);
      gload_lds16(B + (size_t)(n0 + row) * 512 + kt * 32 + scol, Bs + i * 512);
    }
    __syncthreads();
    bf16x8 av[4], bv[4];
#pragma unroll
    for (int f = 0; f < 4; ++f) {
      av[f] = *(const bf16x8*)(As + (wm * 64 + f * 16 + lm) * 32 + q * 8);
      bv[f] = *(const bf16x8*)(Bs + (wn * 64 + f * 16 + lm) * 32 + q * 8);
    }
#pragma unroll
    for (int fm = 0; fm < 4; ++fm)
#pragma unroll
      for (int fn = 0; fn < 4; ++fn)
        acc[fm][fn] = __builtin_amdgcn_mfma_f32_16x16x32_bf16(av[fm], bv[fn], acc[fm][fn], 0, 0, 0);
    __syncthreads();
  }
#pragma unroll
  for (int fn = 0; fn < 4; ++fn) {
    int g = n0 + wn * 64 + fn * 16 + lm;
    float bi = bias[g];
#pragma unroll
    for (int fm = 0; fm < 4; ++fm) {
      int rb = m0 + wm * 64 + fm * 16 + q * 4;
#pragma unroll
      for (int r = 0; r < 4; ++r)
        out[(size_t)(rb + r) * G3 + g] = acc[fm][fn][r] + bi;
    }
  }
}

// ---------------- phase 2: persistent GRU scan ----------------
// 256 blocks = 16 groups (16 batch rows each) x 16 gate-slice blocks (96 W_hh rows in VGPRs)
// 192 threads = 3 waves; wave p handles gate p (r/z/n), 2 N-tiles of 16.
__global__ __launch_bounds__(192) void scan_kernel(const float* __restrict__ gi,
                                                   const short* __restrict__ Whh,
                                                   const float* __restrict__ bias_hh,
                                                   short* __restrict__ hbuf,
                                                   unsigned* __restrict__ counters,
                                                   float* __restrict__ hmaster,
                                                   int CH, int step_base, int first) {
  int bid = blockIdx.x;
  int xcd = bid & 7, slot = bid >> 3;
  int group = xcd + 8 * (slot >> 4);
  int j = slot & 15;
  int tid = threadIdx.x;
  int w = tid >> 6, lane = tid & 63;
  int lm = lane & 15, q = lane >> 4;
  int grow = group * 16;

  __shared__ short h_lds[16 * 520];      // padded rows: 512+8
  __shared__ float gh_lds[16][100];
  __shared__ float h_loc[512];           // [16][32] fp32 master slice
  __shared__ float bhh[96];

  // W_hh slice into registers: wave w -> gate w, tiles tau in {0,1}
  bf16x8 Bf[2][16];
#pragma unroll
  for (int tau = 0; tau < 2; ++tau)
#pragma unroll
    for (int kt = 0; kt < 16; ++kt) {
      int row = w * 512 + j * 32 + tau * 16 + lm;
      Bf[tau][kt] = *(const bf16x8*)(Whh + (size_t)row * 512 + kt * 32 + q * 8);
    }

  for (int c0 = tid; c0 < 96; c0 += 192) {
    int p = c0 >> 5, cc = c0 & 31;
    bhh[c0] = bias_hh[p * 512 + j * 32 + cc];
  }
  for (int idx = tid; idx < 512; idx += 192) {
    int r = idx >> 5, cc = idx & 31;
    h_loc[idx] = first ? 0.0f : hmaster[(size_t)(grow + r) * 512 + j * 32 + cc];
  }
  __syncthreads();

  for (int t = 0; t < CH; ++t) {
    int gstep = step_base + t;
    int p = gstep & 1;
    const short* hsrc = hbuf + (size_t)p * (256 * 512) + (size_t)grow * 512;

    // prefetch gi for this step (independent of h)
    const float* gbase = gi + ((size_t)t * 256 + grow) * G3 + j * 32;
    float gir[3], giz[3], gin[3];
#pragma unroll
    for (int u = 0; u < 3; ++u) {
      int idx = tid + u * 192;
      if (idx < 512) {
        int r = idx >> 5, cc = idx & 31;
        const float* gp = gbase + (size_t)r * G3 + cc;
        gir[u] = gp[0]; giz[u] = gp[512]; gin[u] = gp[1024];
      }
    }

    // stage h (bf16) -> LDS with +8 row pad
    for (int i = tid; i < 1024; i += 192) {
      int r = i >> 6, ck = i & 63;
      *(bf16x8*)(h_lds + r * 520 + ck * 8) = *(const bf16x8*)(hsrc + r * 512 + ck * 8);
    }
    __syncthreads();

    // MFMA: gh[16 x 32] for this wave's gate
    f32x4 a0 = {0.f, 0.f, 0.f, 0.f}, a1 = {0.f, 0.f, 0.f, 0.f};
#pragma unroll
    for (int kt = 0; kt < 16; ++kt) {
      bf16x8 a = *(const bf16x8*)(h_lds + lm * 520 + kt * 32 + q * 8);
      a0 = __builtin_amdgcn_mfma_f32_16x16x32_bf16(a, Bf[0][kt], a0, 0, 0, 0);
      a1 = __builtin_amdgcn_mfma_f32_16x16x32_bf16(a, Bf[1][kt], a1, 0, 0, 0);
    }
#pragma unroll
    for (int r = 0; r < 4; ++r) {
      gh_lds[q * 4 + r][w * 32 + lm]      = a0[r];
      gh_lds[q * 4 + r][w * 32 + 16 + lm] = a1[r];
    }
    __syncthreads();

    // elementwise GRU cell, fp32 state
    short* hdst = hbuf + (size_t)(1 - p) * (256 * 512);
#pragma unroll
    for (int u = 0; u < 3; ++u) {
      int idx = tid + u * 192;
      if (idx < 512) {
        int r = idx >> 5, cc = idx & 31;
        float hr = gh_lds[r][cc]      + bhh[cc];
        float hz = gh_lds[r][32 + cc] + bhh[32 + cc];
        float hn = gh_lds[r][64 + cc] + bhh[64 + cc];
        float rr = sigmoid_f(gir[u] + hr);
        float zz = sigmoid_f(giz[u] + hz);
        float nn = tanh_f(gin[u] + rr * hn);
        float ho = h_loc[idx];
        float hv = (1.0f - zz) * nn + zz * ho;
        h_loc[idx] = hv;
        hdst[(size_t)(grow + r) * 512 + j * 32 + cc] = f2bs(hv);
      }
    }
    __syncthreads();

    // per-group barrier: arrive always, wait except on last step of chunk
    if (tid == 0) {
      __hip_atomic_fetch_add(&counters[group], 1u, __ATOMIC_RELEASE, __HIP_MEMORY_SCOPE_AGENT);
      if (t < CH - 1) {
        unsigned tgt = 16u * (unsigned)(gstep + 1);
        int it = 0;
        while (__hip_atomic_load(&counters[group], __ATOMIC_ACQUIRE, __HIP_MEMORY_SCOPE_AGENT) < tgt) {
          __builtin_amdgcn_s_sleep(1);
          if (++it > (1 << 18)) break;   // bounded: wrong answer beats a hang
        }
      }
    }
    __syncthreads();
  }

  // write fp32 state back (d_out doubles as h_master)
  for (int idx = tid; idx < 512; idx += 192) {
    int r = idx >> 5, cc = idx & 31;
    hmaster[(size_t)(grow + r) * 512 + j * 32 + cc] = h_loc[idx];
  }
}

// ---------------- host ----------------
extern "C" void kernel_launch(void* const* d_in, const int* in_sizes, int n_in,
                              void* d_out, int out_size, void* d_ws, size_t ws_size,
                              hipStream_t stream) {
  const float* x   = (const float*)d_in[0];
  const float* Wih = (const float*)d_in[1];
  const float* Whh = (const float*)d_in[2];
  const float* bih = (const float*)d_in[3];
  const float* bhh = (const float*)d_in[4];
  float* out = (float*)d_out;
  char* ws = (char*)d_ws;

  const size_t XT_BYTES   = (size_t)256 * 256 * 512 * 2;  // 64 MiB
  const size_t W_BYTES    = (size_t)1536 * 512 * 2;       // 1.5 MiB
  const size_t HBUF_BYTES = (size_t)2 * 256 * 512 * 2;    // 512 KiB
  const size_t CNT_BYTES  = 1024;
  const size_t FIXED = XT_BYTES + 2 * W_BYTES + HBUF_BYTES + CNT_BYTES + 4096;

  int CH = 256;
  while (CH > 4 && FIXED + (size_t)CH * 256 * G3 * 4 > ws_size) CH >>= 1;

  size_t off = 0;
  float* gi = (float*)(ws + off);          off += (size_t)CH * 256 * G3 * 4;
  short* xT = (short*)(ws + off);          off += XT_BYTES;
  short* WihB = (short*)(ws + off);        off += W_BYTES;
  short* WhhB = (short*)(ws + off);        off += W_BYTES;
  short* hbuf = (short*)(ws + off);        off += HBUF_BYTES;
  unsigned* counters = (unsigned*)(ws + off);

  hipMemsetAsync(hbuf, 0, HBUF_BYTES + CNT_BYTES, stream);

  convert_kernel<<<768, 256, 0, stream>>>(Wih, WihB, 196608);
  convert_kernel<<<768, 256, 0, stream>>>(Whh, WhhB, 196608);
  transpose_kernel<<<32768, 256, 0, stream>>>(x, xT);

  int nch = 256 / CH;
  for (int c = 0; c < nch; ++c) {
    int M = CH * 256;
    phase1_kernel<<<(M / 128) * 12, 256, 0, stream>>>(
        xT + (size_t)c * CH * 256 * 512, WihB, bih, gi, M);
    scan_kernel<<<256, 192, 0, stream>>>(gi, WhhB, bhh, hbuf, counters, out,
                                         CH, c * CH, c == 0 ? 1 : 0);
  }
}

// Round 2
// 1221.709 us; speedup vs baseline: 2.3358x; 2.3358x over previous
//
#include <hip/hip_runtime.h>
#include <stdint.h>

// ---------------- types ----------------
typedef __attribute__((ext_vector_type(8))) short bf16x8;   // 8 x bf16 = 4 VGPRs
typedef __attribute__((ext_vector_type(4))) short s16x4;    // 4 x bf16 = 8B
typedef __attribute__((ext_vector_type(4))) float f32x4;

#define AS1 __attribute__((address_space(1)))
#define AS3 __attribute__((address_space(3)))

static __device__ __forceinline__ void gload_lds16(const void* g, void* l) {
  __builtin_amdgcn_global_load_lds((const AS1 unsigned int*)g,
                                   (AS3 unsigned int*)l, 16, 0, 0);
}

// round-to-nearest-even f32 -> bf16 bits
static __device__ __forceinline__ short f2bs(float f) {
  unsigned u = __builtin_bit_cast(unsigned, f);
  unsigned r = (u + 0x7fffu + ((u >> 16) & 1u)) >> 16;
  return (short)r;
}

static __device__ __forceinline__ float sigmoid_f(float x) {
  return 1.0f / (1.0f + __expf(-x));
}
static __device__ __forceinline__ float tanh_f(float x) {
  float ax = fabsf(x);
  float e  = __expf(-2.0f * ax);
  float t  = (1.0f - e) / (1.0f + e);
  return copysignf(t, x);
}

// constants
#define BATCH 256
#define HID   512
#define STEPS 256
#define G3    1536   // 3*HID

// ---------------- fp32 -> bf16 convert (weights) ----------------
__global__ __launch_bounds__(256) void convert_kernel(const float* __restrict__ src,
                                                      short* __restrict__ dst, int n4) {
  int i = blockIdx.x * 256 + threadIdx.x;
  if (i < n4) {
    float4 v = *(const float4*)(src + (size_t)i * 4);
    s16x4 o;
    o[0] = f2bs(v.x); o[1] = f2bs(v.y); o[2] = f2bs(v.z); o[3] = f2bs(v.w);
    *(s16x4*)(dst + (size_t)i * 4) = o;
  }
}

// ---------------- x[b][i][s] f32  ->  xT[s][b][i] bf16 ----------------
__global__ __launch_bounds__(256) void transpose_kernel(const float* __restrict__ x,
                                                        short* __restrict__ xT) {
  int bx = blockIdx.x;
  int st = bx & 7, it = (bx >> 3) & 15, b = bx >> 7;
  int s0 = st * 32, i0 = it * 32;
  int tid = threadIdx.x;
  __shared__ float tile[32][33];
  int il = tid >> 3, s4 = (tid & 7) * 4;
  float4 v = *(const float4*)(x + (size_t)b * 131072 + (size_t)(i0 + il) * 256 + s0 + s4);
  tile[il][s4 + 0] = v.x; tile[il][s4 + 1] = v.y;
  tile[il][s4 + 2] = v.z; tile[il][s4 + 3] = v.w;
  __syncthreads();
  int sl = tid >> 3, iv = (tid & 7) * 4;
  s16x4 o;
  o[0] = f2bs(tile[iv + 0][sl]); o[1] = f2bs(tile[iv + 1][sl]);
  o[2] = f2bs(tile[iv + 2][sl]); o[3] = f2bs(tile[iv + 3][sl]);
  *(s16x4*)(xT + (size_t)(s0 + sl) * 131072 + (size_t)b * 512 + i0 + iv) = o;
}

// ---------------- phase 1: gi[m][g] = xT[m] . W_ih[g] + bias_ih[g] ----------------
// C[M x 1536] = A[M x 512] * B[1536 x 512]^T ; 128x128 tiles, BK=32, 256 thr (4 waves)
__global__ __launch_bounds__(256) void phase1_kernel(const short* __restrict__ A,
                                                     const short* __restrict__ B,
                                                     const float* __restrict__ bias,
                                                     float* __restrict__ out, int M) {
  int MT = M >> 7;
  int bx = blockIdx.x;
  int mt = bx % MT, nt = bx / MT;
  int m0 = mt * 128, n0 = nt * 128;
  int tid = threadIdx.x, w = tid >> 6, lane = tid & 63;
  int lm = lane & 15, q = lane >> 4;
  int wm = w & 1, wn = w >> 1;
  __shared__ short As[128 * 32];
  __shared__ short Bs[128 * 32];
  f32x4 acc[4][4] = {};
  int srow = lane >> 2;          // 0..15
  int scol = (lane & 3) * 8;     // element offset within 32

  for (int kt = 0; kt < 16; ++kt) {
#pragma unroll
    for (int i2 = 0; i2 < 2; ++i2) {
      int i = w * 2 + i2;
      int row = i * 16 + srow;
      gload_lds16(A + (size_t)(m0 + row) * 512 + kt * 32 + scol, As + i * 512);
      gload_lds16(B + (size_t)(n0 + row) * 512 + kt * 32 + scol, Bs + i * 512);
    }
    __syncthreads();
    bf16x8 av[4], bv[4];
#pragma unroll
    for (int f = 0; f < 4; ++f) {
      av[f] = *(const bf16x8*)(As + (wm * 64 + f * 16 + lm) * 32 + q * 8);
      bv[f] = *(const bf16x8*)(Bs + (wn * 64 + f * 16 + lm) * 32 + q * 8);
    }
#pragma unroll
    for (int fm = 0; fm < 4; ++fm)
#pragma unroll
      for (int fn = 0; fn < 4; ++fn)
        acc[fm][fn] = __builtin_amdgcn_mfma_f32_16x16x32_bf16(av[fm], bv[fn], acc[fm][fn], 0, 0, 0);
    __syncthreads();
  }
#pragma unroll
  for (int fn = 0; fn < 4; ++fn) {
    int g = n0 + wn * 64 + fn * 16 + lm;
    float bi = bias[g];
#pragma unroll
    for (int fm = 0; fm < 4; ++fm) {
      int rb = m0 + wm * 64 + fm * 16 + q * 4;
#pragma unroll
      for (int r = 0; r < 4; ++r)
        out[(size_t)(rb + r) * G3 + g] = acc[fm][fn][r] + bi;
    }
  }
}

// ---------------- phase 2: persistent GRU scan ----------------
// 256 blocks = 16 groups (16 batch rows) x 16 gate-slice blocks (96 W_hh rows in regs).
// 256 threads = 4 waves; waves 0-2 -> gates r/z/n (2 N-tiles of 16 each); wave 3 helps
// staging/elementwise only.
// Cross-block h exchange + barrier use inline-asm sc0+sc1 (coherent, L3-served)
// accesses with manual vmcnt ordering — NO acquire/release (avoids buffer_inv /
// buffer_wbl2 whole-L2 maintenance, which was 10us/step in round 1).
__global__ __launch_bounds__(256) void scan_kernel(const float* __restrict__ gi,
                                                   const short* __restrict__ Whh,
                                                   const float* __restrict__ bias_hh,
                                                   short* __restrict__ hbuf,
                                                   unsigned* __restrict__ counters,
                                                   float* __restrict__ hmaster,
                                                   int CH, int step_base, int first) {
  int bid = blockIdx.x;
  int xcd = bid & 7, slot = bid >> 3;
  int group = xcd + 8 * (slot >> 4);   // 16 blocks of a group share (heuristic) XCD for L2 gi locality
  int j = slot & 15;
  int tid = threadIdx.x;
  int w = tid >> 6, lane = tid & 63;
  int lm = lane & 15, q = lane >> 4;
  int grow = group * 16;

  __shared__ short h_lds[16 * 520];      // padded rows: 512+8
  __shared__ float gh_lds[16][100];
  __shared__ float h_loc[512];           // [16][32] fp32 master slice
  __shared__ float bhh[96];

  // W_hh slice into registers: wave w (<3) -> gate w, 2 N-tiles of 16
  bf16x8 Bf[2][16];
  if (w < 3) {
#pragma unroll
    for (int tau = 0; tau < 2; ++tau)
#pragma unroll
      for (int kt = 0; kt < 16; ++kt) {
        int row = w * 512 + j * 32 + tau * 16 + lm;
        Bf[tau][kt] = *(const bf16x8*)(Whh + (size_t)row * 512 + kt * 32 + q * 8);
      }
  }

  if (tid < 96) {
    int p = tid >> 5, cc = tid & 31;
    bhh[tid] = bias_hh[p * 512 + j * 32 + cc];
  }
#pragma unroll
  for (int u = 0; u < 2; ++u) {
    int idx = tid + u * 256;
    int r = idx >> 5, cc = idx & 31;
    h_loc[idx] = first ? 0.0f : hmaster[(size_t)(grow + r) * 512 + j * 32 + cc];
  }
  __syncthreads();

  for (int t = 0; t < CH; ++t) {
    int gstep = step_base + t;
    int p = gstep & 1;
    const short* hsrc = hbuf + (size_t)p * (256 * 512) + (size_t)grow * 512;

    // gi prefetch for this step (plain cached loads; latency shared with h staging wait)
    const float* gbase = gi + ((size_t)t * 256 + grow) * G3 + j * 32;
    float gir[2], giz[2], gin[2];
#pragma unroll
    for (int u = 0; u < 2; ++u) {
      int idx = tid + u * 256;
      int r = idx >> 5, cc = idx & 31;
      const float* gp = gbase + (size_t)r * G3 + cc;
      gir[u] = gp[0]; giz[u] = gp[512]; gin[u] = gp[1024];
    }

    // stage h: 1024 16B chunks / 256 threads = 4 each; coherent loads (sc0 sc1),
    // single vmcnt(0) inside one asm block so data is valid at the LDS writes.
    {
      const short* pa = hsrc + (size_t)(tid >> 6) * 512 + (size_t)(tid & 63) * 8;
      bf16x8 t0, t1, t2, t3;
      asm volatile(
          "global_load_dwordx4 %0, %4, off sc0 sc1\n\t"
          "global_load_dwordx4 %1, %5, off sc0 sc1\n\t"
          "global_load_dwordx4 %2, %6, off sc0 sc1\n\t"
          "global_load_dwordx4 %3, %7, off sc0 sc1\n\t"
          "s_waitcnt vmcnt(0)"
          : "=&v"(t0), "=&v"(t1), "=&v"(t2), "=&v"(t3)
          : "v"(pa), "v"(pa + 2048), "v"(pa + 4096), "v"(pa + 6144)
          : "memory");
      short* ld = h_lds + (tid >> 6) * 520 + (tid & 63) * 8;
      *(bf16x8*)(ld)            = t0;
      *(bf16x8*)(ld + 4 * 520)  = t1;
      *(bf16x8*)(ld + 8 * 520)  = t2;
      *(bf16x8*)(ld + 12 * 520) = t3;
    }
    __syncthreads();

    // MFMA: gh[16 x 32] for this wave's gate; 4 independent acc chains to halve
    // dependent-MFMA latency exposure.
    if (w < 3) {
      f32x4 a0 = {0.f,0.f,0.f,0.f}, a1 = {0.f,0.f,0.f,0.f};
      f32x4 a2 = {0.f,0.f,0.f,0.f}, a3 = {0.f,0.f,0.f,0.f};
#pragma unroll
      for (int kt = 0; kt < 8; ++kt) {
        bf16x8 a = *(const bf16x8*)(h_lds + lm * 520 + kt * 32 + q * 8);
        a0 = __builtin_amdgcn_mfma_f32_16x16x32_bf16(a, Bf[0][kt], a0, 0, 0, 0);
        a1 = __builtin_amdgcn_mfma_f32_16x16x32_bf16(a, Bf[1][kt], a1, 0, 0, 0);
      }
#pragma unroll
      for (int kt = 8; kt < 16; ++kt) {
        bf16x8 a = *(const bf16x8*)(h_lds + lm * 520 + kt * 32 + q * 8);
        a2 = __builtin_amdgcn_mfma_f32_16x16x32_bf16(a, Bf[0][kt], a2, 0, 0, 0);
        a3 = __builtin_amdgcn_mfma_f32_16x16x32_bf16(a, Bf[1][kt], a3, 0, 0, 0);
      }
#pragma unroll
      for (int r = 0; r < 4; ++r) {
        gh_lds[q * 4 + r][w * 32 + lm]      = a0[r] + a2[r];
        gh_lds[q * 4 + r][w * 32 + 16 + lm] = a1[r] + a3[r];
      }
    }
    __syncthreads();

    // elementwise GRU cell, fp32 state in LDS
#pragma unroll
    for (int u = 0; u < 2; ++u) {
      int idx = tid + u * 256;
      int r = idx >> 5, cc = idx & 31;
      float hr = gh_lds[r][cc]      + bhh[cc];
      float hz = gh_lds[r][32 + cc] + bhh[32 + cc];
      float hn = gh_lds[r][64 + cc] + bhh[64 + cc];
      float rr = sigmoid_f(gir[u] + hr);
      float zz = sigmoid_f(giz[u] + hz);
      float nn = tanh_f(gin[u] + rr * hn);
      float hv = (1.0f - zz) * nn + zz * h_loc[idx];
      h_loc[idx] = hv;
    }
    __syncthreads();

    // publish h (wave 0: 64 lanes x 16B = full 1KB slice), then flag, then wait.
    if (w == 0) {
      short* hdst = hbuf + (size_t)(1 - p) * (256 * 512)
                  + (size_t)(grow + (lane >> 2)) * 512 + j * 32 + (lane & 3) * 8;
      int base = (lane >> 2) * 32 + (lane & 3) * 8;
      bf16x8 hb;
#pragma unroll
      for (int e = 0; e < 8; ++e) hb[e] = f2bs(h_loc[base + e]);
      // coherent write-through + ack at the coherence point before flag store
      asm volatile("global_store_dwordx4 %0, %1, off sc0 sc1\n\t"
                   "s_waitcnt vmcnt(0)"
                   :: "v"(hdst), "v"(hb) : "memory");
      if (lane == 0) {
        unsigned* cp = counters + (size_t)(group * 16 + j) * 16;  // 64B-padded slot
        unsigned val = (unsigned)(gstep + 1);
        asm volatile("global_store_dword %0, %1, off sc0 sc1" :: "v"(cp), "v"(val) : "memory");
      }
      if (t < CH - 1 && lane < 16) {
        const unsigned* cp = counters + (size_t)(group * 16 + lane) * 16;
        unsigned tgt = (unsigned)(gstep + 1);
        unsigned v; int it = 0;
        do {
          asm volatile("global_load_dword %0, %1, off sc0 sc1\n\t"
                       "s_waitcnt vmcnt(0)"
                       : "=v"(v) : "v"(cp) : "memory");
          if (v >= tgt) break;
          __builtin_amdgcn_s_sleep(1);
        } while (++it < (1 << 20));   // bounded: wrong answer beats a hang
      }
    }
    __syncthreads();
  }

  // write fp32 state back (d_out doubles as h_master across chunk launches)
#pragma unroll
  for (int u = 0; u < 2; ++u) {
    int idx = tid + u * 256;
    int r = idx >> 5, cc = idx & 31;
    hmaster[(size_t)(grow + r) * 512 + j * 32 + cc] = h_loc[idx];
  }
}

// ---------------- host ----------------
extern "C" void kernel_launch(void* const* d_in, const int* in_sizes, int n_in,
                              void* d_out, int out_size, void* d_ws, size_t ws_size,
                              hipStream_t stream) {
  const float* x   = (const float*)d_in[0];
  const float* Wih = (const float*)d_in[1];
  const float* Whh = (const float*)d_in[2];
  const float* bih = (const float*)d_in[3];
  const float* bhh = (const float*)d_in[4];
  float* out = (float*)d_out;
  char* ws = (char*)d_ws;

  const size_t XT_BYTES   = (size_t)256 * 256 * 512 * 2;  // 64 MiB
  const size_t W_BYTES    = (size_t)1536 * 512 * 2;       // 1.5 MiB
  const size_t HBUF_BYTES = (size_t)2 * 256 * 512 * 2;    // 512 KiB
  const size_t CNT_BYTES  = 16 * 16 * 64;                 // 16 KiB (64B-padded slots)
  const size_t FIXED = XT_BYTES + 2 * W_BYTES + HBUF_BYTES + CNT_BYTES + 4096;

  int CH = 256;
  while (CH > 4 && FIXED + (size_t)CH * 256 * G3 * 4 > ws_size) CH >>= 1;

  size_t off = 0;
  float* gi = (float*)(ws + off);          off += (size_t)CH * 256 * G3 * 4;
  short* xT = (short*)(ws + off);          off += XT_BYTES;
  short* WihB = (short*)(ws + off);        off += W_BYTES;
  short* WhhB = (short*)(ws + off);        off += W_BYTES;
  short* hbuf = (short*)(ws + off);        off += HBUF_BYTES;
  unsigned* counters = (unsigned*)(ws + off);

  hipMemsetAsync(hbuf, 0, HBUF_BYTES + CNT_BYTES, stream);

  convert_kernel<<<768, 256, 0, stream>>>(Wih, WihB, 196608);
  convert_kernel<<<768, 256, 0, stream>>>(Whh, WhhB, 196608);
  transpose_kernel<<<32768, 256, 0, stream>>>(x, xT);

  int nch = 256 / CH;
  for (int c = 0; c < nch; ++c) {
    int M = CH * 256;
    phase1_kernel<<<(M / 128) * 12, 256, 0, stream>>>(
        xT + (size_t)c * CH * 256 * 512, WihB, bih, gi, M);
    scan_kernel<<<256, 256, 0, stream>>>(gi, WhhB, bhh, hbuf, counters, out,
                                         CH, c * CH, c == 0 ? 1 : 0);
  }
}

// Round 4
// 1069.247 us; speedup vs baseline: 2.6688x; 1.1426x over previous
//
#include <hip/hip_runtime.h>
#include <stdint.h>

// ---------------- types ----------------
typedef __attribute__((ext_vector_type(8))) short bf16x8;   // 8 x bf16 = 4 VGPRs
typedef __attribute__((ext_vector_type(4))) short s16x4;    // 4 x bf16 = 8B
typedef __attribute__((ext_vector_type(4))) float f32x4;

#define AS1 __attribute__((address_space(1)))
#define AS3 __attribute__((address_space(3)))

static __device__ __forceinline__ void gload_lds16(const void* g, void* l) {
  __builtin_amdgcn_global_load_lds((const AS1 unsigned int*)g,
                                   (AS3 unsigned int*)l, 16, 0, 0);
}

// round-to-nearest-even f32 -> bf16 bits
static __device__ __forceinline__ short f2bs(float f) {
  unsigned u = __builtin_bit_cast(unsigned, f);
  unsigned r = (u + 0x7fffu + ((u >> 16) & 1u)) >> 16;
  return (short)r;
}
static __device__ __forceinline__ float bs2f(short s) {
  unsigned u = ((unsigned)(unsigned short)s) << 16;
  return __builtin_bit_cast(float, u);
}

static __device__ __forceinline__ float sigmoid_f(float x) {
  return 1.0f / (1.0f + __expf(-x));
}
static __device__ __forceinline__ float tanh_f(float x) {
  float ax = fabsf(x);
  float e  = __expf(-2.0f * ax);
  float t  = (1.0f - e) / (1.0f + e);
  return copysignf(t, x);
}

// constants
#define BATCH 256
#define HID   512
#define STEPS 256
#define G3    1536   // 3*HID

// ---------------- fp32 -> bf16 convert (weights) ----------------
__global__ __launch_bounds__(256) void convert_kernel(const float* __restrict__ src,
                                                      short* __restrict__ dst, int n4) {
  int i = blockIdx.x * 256 + threadIdx.x;
  if (i < n4) {
    float4 v = *(const float4*)(src + (size_t)i * 4);
    s16x4 o;
    o[0] = f2bs(v.x); o[1] = f2bs(v.y); o[2] = f2bs(v.z); o[3] = f2bs(v.w);
    *(s16x4*)(dst + (size_t)i * 4) = o;
  }
}

// ---------------- x[b][i][s] f32  ->  xT[s][b][i] bf16 ----------------
__global__ __launch_bounds__(256) void transpose_kernel(const float* __restrict__ x,
                                                        short* __restrict__ xT) {
  int bx = blockIdx.x;
  int st = bx & 7, it = (bx >> 3) & 15, b = bx >> 7;
  int s0 = st * 32, i0 = it * 32;
  int tid = threadIdx.x;
  __shared__ float tile[32][33];
  int il = tid >> 3, s4 = (tid & 7) * 4;
  float4 v = *(const float4*)(x + (size_t)b * 131072 + (size_t)(i0 + il) * 256 + s0 + s4);
  tile[il][s4 + 0] = v.x; tile[il][s4 + 1] = v.y;
  tile[il][s4 + 2] = v.z; tile[il][s4 + 3] = v.w;
  __syncthreads();
  int sl = tid >> 3, iv = (tid & 7) * 4;
  s16x4 o;
  o[0] = f2bs(tile[iv + 0][sl]); o[1] = f2bs(tile[iv + 1][sl]);
  o[2] = f2bs(tile[iv + 2][sl]); o[3] = f2bs(tile[iv + 3][sl]);
  *(s16x4*)(xT + (size_t)(s0 + sl) * 131072 + (size_t)b * 512 + i0 + iv) = o;
}

// ---------------- phase 1: gi[m][g] = xT[m] . W_ih[g] + bias_ih[g] (bf16 out) ----
__global__ __launch_bounds__(256) void phase1_kernel(const short* __restrict__ A,
                                                     const short* __restrict__ B,
                                                     const float* __restrict__ bias,
                                                     short* __restrict__ out, int M) {
  int MT = M >> 7;
  int bx = blockIdx.x;
  int mt = bx % MT, nt = bx / MT;
  int m0 = mt * 128, n0 = nt * 128;
  int tid = threadIdx.x, w = tid >> 6, lane = tid & 63;
  int lm = lane & 15, q = lane >> 4;
  int wm = w & 1, wn = w >> 1;
  __shared__ short As[128 * 32];
  __shared__ short Bs[128 * 32];
  f32x4 acc[4][4] = {};
  int srow = lane >> 2;
  int scol = (lane & 3) * 8;

  for (int kt = 0; kt < 16; ++kt) {
#pragma unroll
    for (int i2 = 0; i2 < 2; ++i2) {
      int i = w * 2 + i2;
      int row = i * 16 + srow;
      gload_lds16(A + (size_t)(m0 + row) * 512 + kt * 32 + scol, As + i * 512);
      gload_lds16(B + (size_t)(n0 + row) * 512 + kt * 32 + scol, Bs + i * 512);
    }
    __syncthreads();
    bf16x8 av[4], bv[4];
#pragma unroll
    for (int f = 0; f < 4; ++f) {
      av[f] = *(const bf16x8*)(As + (wm * 64 + f * 16 + lm) * 32 + q * 8);
      bv[f] = *(const bf16x8*)(Bs + (wn * 64 + f * 16 + lm) * 32 + q * 8);
    }
#pragma unroll
    for (int fm = 0; fm < 4; ++fm)
#pragma unroll
      for (int fn = 0; fn < 4; ++fn)
        acc[fm][fn] = __builtin_amdgcn_mfma_f32_16x16x32_bf16(av[fm], bv[fn], acc[fm][fn], 0, 0, 0);
    __syncthreads();
  }
#pragma unroll
  for (int fn = 0; fn < 4; ++fn) {
    int g = n0 + wn * 64 + fn * 16 + lm;
    float bi = bias[g];
#pragma unroll
    for (int fm = 0; fm < 4; ++fm) {
      int rb = m0 + wm * 64 + fm * 16 + q * 4;
#pragma unroll
      for (int r = 0; r < 4; ++r)
        out[(size_t)(rb + r) * G3 + g] = f2bs(acc[fm][fn][r] + bi);
    }
  }
}

// ---------------- phase 2: persistent GRU scan ----------------
// 16 groups (16 batch rows) x 16 gate-slice blocks (96 W_hh rows in regs).
// All cross-block sync via sc0+sc1 (device coherence point) — the ONLY verified
// coherent path on gfx950 (R3's sc0-only same-XCD fast path was NOT coherent).
// Latency structure per step:
//   stage-RT -> mfma/elementwise -> { wave0: publish+ack+flag  ||  wave1: poll peers }
// The poll overlaps the publish ack (peers' flags arrive independently).
__global__ __launch_bounds__(256) void scan_kernel(const short* __restrict__ gi,
                                                   const short* __restrict__ Whh,
                                                   const float* __restrict__ bias_hh,
                                                   short* __restrict__ hbuf,
                                                   unsigned* __restrict__ counters,
                                                   float* __restrict__ hmaster,
                                                   int CH, int step_base, int first) {
  int bid = blockIdx.x;
  int xcd = bid & 7, slot = bid >> 3;
  int group = xcd + 8 * (slot >> 4);
  int j = slot & 15;
  int tid = threadIdx.x;
  int w = tid >> 6, lane = tid & 63;
  int lm = lane & 15, q = lane >> 4;
  int grow = group * 16;

  __shared__ short h_lds[16 * 520];      // padded rows: 512+8
  __shared__ float gh_lds[16][100];
  __shared__ float h_loc[512];           // [16][32] fp32 master slice
  __shared__ float bhh[96];

  // W_hh slice into registers: wave w (<3) -> gate w, 2 N-tiles of 16
  bf16x8 Bf[2][16];
  if (w < 3) {
#pragma unroll
    for (int tau = 0; tau < 2; ++tau)
#pragma unroll
      for (int kt = 0; kt < 16; ++kt) {
        int row = w * 512 + j * 32 + tau * 16 + lm;
        Bf[tau][kt] = *(const bf16x8*)(Whh + (size_t)row * 512 + kt * 32 + q * 8);
      }
  }

  if (tid < 96) {
    int p = tid >> 5, cc = tid & 31;
    bhh[tid] = bias_hh[p * 512 + j * 32 + cc];
  }
#pragma unroll
  for (int u = 0; u < 2; ++u) {
    int idx = tid + u * 256;
    int r = idx >> 5, cc = idx & 31;
    h_loc[idx] = first ? 0.0f : hmaster[(size_t)(grow + r) * 512 + j * 32 + cc];
  }
  __syncthreads();

  // per-thread gi pointers (2 elements per thread per gate), bf16
  int i0 = tid, i1 = tid + 256;
  const short* gp0 = gi + (size_t)(grow + (i0 >> 5)) * G3 + j * 32 + (i0 & 31);
  const short* gp1 = gi + (size_t)(grow + (i1 >> 5)) * G3 + j * 32 + (i1 & 31);
  const size_t gstride = (size_t)256 * G3;

  // software prefetch (plain cached loads; compiler inserts the hazard wait at use)
  short pg0r = gp0[0], pg0z = gp0[512], pg0n = gp0[1024];
  short pg1r = gp1[0], pg1z = gp1[512], pg1n = gp1[1024];

  for (int t = 0; t < CH; ++t) {
    int gstep = step_base + t;
    int p = gstep & 1;
    const short* hsrc = hbuf + (size_t)p * (256 * 512) + (size_t)grow * 512;
    const short* pa = hsrc + (size_t)(tid >> 6) * 512 + (size_t)(tid & 63) * 8;

    // stage h: 4 x 16B coherent loads + single vmcnt(0) (h RT only; gi prefetch
    // from the previous iteration is long since complete).
    bf16x8 t0, t1, t2, t3;
    asm volatile(
        "global_load_dwordx4 %0, %4, off sc0 sc1\n\t"
        "global_load_dwordx4 %1, %5, off sc0 sc1\n\t"
        "global_load_dwordx4 %2, %6, off sc0 sc1\n\t"
        "global_load_dwordx4 %3, %7, off sc0 sc1\n\t"
        "s_waitcnt vmcnt(0)"
        : "=&v"(t0), "=&v"(t1), "=&v"(t2), "=&v"(t3)
        : "v"(pa), "v"(pa + 2048), "v"(pa + 4096), "v"(pa + 6144)
        : "memory");

    // consume current gi prefetch; issue next step's (hides under MFMA+publish)
    float cg0r = bs2f(pg0r), cg0z = bs2f(pg0z), cg0n = bs2f(pg0n);
    float cg1r = bs2f(pg1r), cg1z = bs2f(pg1z), cg1n = bs2f(pg1n);
    {
      size_t o = (size_t)((t + 1 < CH) ? (t + 1) : t) * gstride;
      pg0r = gp0[o]; pg0z = gp0[o + 512]; pg0n = gp0[o + 1024];
      pg1r = gp1[o]; pg1z = gp1[o + 512]; pg1n = gp1[o + 1024];
    }

    short* ld = h_lds + (tid >> 6) * 520 + (tid & 63) * 8;
    *(bf16x8*)(ld)            = t0;
    *(bf16x8*)(ld + 4 * 520)  = t1;
    *(bf16x8*)(ld + 8 * 520)  = t2;
    *(bf16x8*)(ld + 12 * 520) = t3;
    __syncthreads();

    // MFMA: gh[16 x 32] for this wave's gate; 4 independent acc chains
    if (w < 3) {
      f32x4 a0 = {0.f,0.f,0.f,0.f}, a1 = {0.f,0.f,0.f,0.f};
      f32x4 a2 = {0.f,0.f,0.f,0.f}, a3 = {0.f,0.f,0.f,0.f};
#pragma unroll
      for (int kt = 0; kt < 8; ++kt) {
        bf16x8 a = *(const bf16x8*)(h_lds + lm * 520 + kt * 32 + q * 8);
        a0 = __builtin_amdgcn_mfma_f32_16x16x32_bf16(a, Bf[0][kt], a0, 0, 0, 0);
        a1 = __builtin_amdgcn_mfma_f32_16x16x32_bf16(a, Bf[1][kt], a1, 0, 0, 0);
      }
#pragma unroll
      for (int kt = 8; kt < 16; ++kt) {
        bf16x8 a = *(const bf16x8*)(h_lds + lm * 520 + kt * 32 + q * 8);
        a2 = __builtin_amdgcn_mfma_f32_16x16x32_bf16(a, Bf[0][kt], a2, 0, 0, 0);
        a3 = __builtin_amdgcn_mfma_f32_16x16x32_bf16(a, Bf[1][kt], a3, 0, 0, 0);
      }
#pragma unroll
      for (int r = 0; r < 4; ++r) {
        gh_lds[q * 4 + r][w * 32 + lm]      = a0[r] + a2[r];
        gh_lds[q * 4 + r][w * 32 + 16 + lm] = a1[r] + a3[r];
      }
    }
    __syncthreads();

    // elementwise GRU cell, fp32 state in LDS
    {
      int r = i0 >> 5, cc = i0 & 31;
      float hr = gh_lds[r][cc]      + bhh[cc];
      float hz = gh_lds[r][32 + cc] + bhh[32 + cc];
      float hn = gh_lds[r][64 + cc] + bhh[64 + cc];
      float rr = sigmoid_f(cg0r + hr);
      float zz = sigmoid_f(cg0z + hz);
      float nn = tanh_f(cg0n + rr * hn);
      h_loc[i0] = (1.0f - zz) * nn + zz * h_loc[i0];
    }
    {
      int r = i1 >> 5, cc = i1 & 31;
      float hr = gh_lds[r][cc]      + bhh[cc];
      float hz = gh_lds[r][32 + cc] + bhh[32 + cc];
      float hn = gh_lds[r][64 + cc] + bhh[64 + cc];
      float rr = sigmoid_f(cg1r + hr);
      float zz = sigmoid_f(cg1z + hz);
      float nn = tanh_f(cg1n + rr * hn);
      h_loc[i1] = (1.0f - zz) * nn + zz * h_loc[i1];
    }
    __syncthreads();

    // wave 0: publish h + ack + flag.  wave 1: poll peers concurrently.
    if (w == 0) {
      short* hdst = hbuf + (size_t)(1 - p) * (256 * 512)
                  + (size_t)(grow + (lane >> 2)) * 512 + j * 32 + (lane & 3) * 8;
      int base = (lane >> 2) * 32 + (lane & 3) * 8;
      bf16x8 hb;
#pragma unroll
      for (int e = 0; e < 8; ++e) hb[e] = f2bs(h_loc[base + e]);
      asm volatile("global_store_dwordx4 %0, %1, off sc0 sc1\n\ts_waitcnt vmcnt(0)"
                   :: "v"(hdst), "v"(hb) : "memory");
      if (lane == 0) {
        unsigned* cp = counters + (size_t)(group * 16 + j) * 16;  // 64B-padded slot
        unsigned val = (unsigned)(gstep + 1);
        asm volatile("global_store_dword %0, %1, off sc0 sc1" :: "v"(cp), "v"(val) : "memory");
      }
    } else if (w == 1) {
      if (t < CH - 1 && lane < 16) {
        const unsigned* cpl = counters + (size_t)(group * 16 + lane) * 16;
        unsigned tgt = (unsigned)(gstep + 1);
        unsigned v; int it = 0;
        do {
          asm volatile("global_load_dword %0, %1, off sc0 sc1\n\ts_waitcnt vmcnt(0)"
                       : "=v"(v) : "v"(cpl) : "memory");
          if (v >= tgt) break;
          __builtin_amdgcn_s_sleep(1);
        } while (++it < (1 << 20));   // bounded: wrong answer beats a hang
      }
    }
    __syncthreads();
  }

  // write fp32 state back (d_out doubles as h_master across chunk launches)
#pragma unroll
  for (int u = 0; u < 2; ++u) {
    int idx = tid + u * 256;
    int r = idx >> 5, cc = idx & 31;
    hmaster[(size_t)(grow + r) * 512 + j * 32 + cc] = h_loc[idx];
  }
}

// ---------------- host ----------------
extern "C" void kernel_launch(void* const* d_in, const int* in_sizes, int n_in,
                              void* d_out, int out_size, void* d_ws, size_t ws_size,
                              hipStream_t stream) {
  const float* x   = (const float*)d_in[0];
  const float* Wih = (const float*)d_in[1];
  const float* Whh = (const float*)d_in[2];
  const float* bih = (const float*)d_in[3];
  const float* bhh = (const float*)d_in[4];
  float* out = (float*)d_out;
  char* ws = (char*)d_ws;

  const size_t XT_BYTES   = (size_t)256 * 256 * 512 * 2;  // 64 MiB
  const size_t W_BYTES    = (size_t)1536 * 512 * 2;       // 1.5 MiB
  const size_t HBUF_BYTES = (size_t)2 * 256 * 512 * 2;    // 512 KiB
  const size_t CNT_BYTES  = 16384;                        // 256 flag slots, 64B padded
  const size_t FIXED = XT_BYTES + 2 * W_BYTES + HBUF_BYTES + CNT_BYTES + 4096;

  int CH = 256;
  while (CH > 4 && FIXED + (size_t)CH * 256 * G3 * 2 > ws_size) CH >>= 1;

  size_t off = 0;
  short* gi = (short*)(ws + off);          off += (size_t)CH * 256 * G3 * 2;
  short* xT = (short*)(ws + off);          off += XT_BYTES;
  short* WihB = (short*)(ws + off);        off += W_BYTES;
  short* WhhB = (short*)(ws + off);        off += W_BYTES;
  short* hbuf = (short*)(ws + off);        off += HBUF_BYTES;
  unsigned* counters = (unsigned*)(ws + off);

  hipMemsetAsync(hbuf, 0, HBUF_BYTES + CNT_BYTES, stream);

  convert_kernel<<<768, 256, 0, stream>>>(Wih, WihB, 196608);
  convert_kernel<<<768, 256, 0, stream>>>(Whh, WhhB, 196608);
  transpose_kernel<<<32768, 256, 0, stream>>>(x, xT);

  int nch = 256 / CH;
  for (int c = 0; c < nch; ++c) {
    int M = CH * 256;
    phase1_kernel<<<(M / 128) * 12, 256, 0, stream>>>(
        xT + (size_t)c * CH * 256 * 512, WihB, bih, gi, M);
    scan_kernel<<<256, 256, 0, stream>>>(gi, WhhB, bhh, hbuf, counters, out,
                                         CH, c * CH, c == 0 ? 1 : 0);
  }
}